// Round 2
// baseline (512.434 us; speedup 1.0000x reference)
//
#include <hip/hip_runtime.h>

typedef float  f32x4 __attribute__((ext_vector_type(4)));
typedef short  s16x8 __attribute__((ext_vector_type(8)));

__device__ __forceinline__ short f2bf(float f) {
  unsigned u = __builtin_bit_cast(unsigned, f);
  u += 0x7FFFu + ((u >> 16) & 1u);   // round-to-nearest-even
  return (short)(u >> 16);
}

// ---------------------------------------------------------------------------
// Kernel 1: Y^T build.  Yt[c][k] = bf16( sum_d x[k][d] * W[d][c] )
// ---------------------------------------------------------------------------
__global__ __launch_bounds__(256) void build_yt(
    const float* __restrict__ xv, const float* __restrict__ xe,
    const float* __restrict__ xf,
    const float* __restrict__ Wv2v, const float* __restrict__ Wv2e,
    const float* __restrict__ We2e, const float* __restrict__ We2f,
    const float* __restrict__ Wf2f, short* __restrict__ Yt)
{
  int bid = blockIdx.x;
  const float* x; const float* W; int K, Kpad; size_t yoff;
  if (bid < 24)       { x=xv; W=Wv2v; K=6000;  Kpad=6016;  yoff=0;       }
  else if (bid < 48)  { x=xv; W=Wv2e; K=6000;  Kpad=6016;  yoff=192512;  bid-=24; }
  else if (bid < 95)  { x=xe; W=We2e; K=12000; Kpad=12000; yoff=385024;  bid-=48; }
  else if (bid < 142) { x=xe; W=We2f; K=12000; Kpad=12000; yoff=769024;  bid-=95; }
  else                { x=xf; W=Wf2f; K=8000;  Kpad=8000;  yoff=1153024; bid-=142; }

  __shared__ float Wl[32][32];
  int tid = threadIdx.x;
  #pragma unroll
  for (int i = 0; i < 4; ++i) {
    int e = tid + i * 256;
    Wl[e >> 5][e & 31] = W[e];
  }
  __syncthreads();

  int row = bid * 256 + tid;
  if (row >= Kpad) return;

  float acc[32];
  #pragma unroll
  for (int c = 0; c < 32; ++c) acc[c] = 0.f;

  if (row < K) {
    const float* xp = x + (size_t)row * 32;
    float xr[32];
    #pragma unroll
    for (int i = 0; i < 8; ++i) {
      f32x4 v = *(const f32x4*)(xp + i * 4);
      xr[i*4+0] = v.x; xr[i*4+1] = v.y; xr[i*4+2] = v.z; xr[i*4+3] = v.w;
    }
    #pragma unroll
    for (int d = 0; d < 32; ++d) {
      float xd = xr[d];
      #pragma unroll
      for (int c = 0; c < 32; ++c) acc[c] += xd * Wl[d][c];
    }
  }
  #pragma unroll
  for (int c = 0; c < 32; ++c)
    Yt[yoff + (size_t)c * Kpad + row] = f2bf(acc[c]);
}

// ---------------------------------------------------------------------------
// Kernel 2: skinny GEMM, 4x-unrolled K loop with batched loads (16 in flight
// per wave) for memory-level parallelism. G loads nontemporal (zero reuse,
// keep Yt resident in L2).
// ---------------------------------------------------------------------------
__device__ __forceinline__ void run_seg(
    const float* __restrict__ G, const short* __restrict__ Yt,
    int K, int Kpad, int row0, int s_lo, int s_hi, int lane,
    f32x4& acc0, f32x4& acc1)
{
  if (s_lo >= s_hi) return;
  int r = lane & 15, g = lane >> 4;
  const float* gp = G + (size_t)(row0 + r) * K;
  const short* b0 = Yt + (size_t)r * Kpad;
  const short* b1 = Yt + (size_t)(r + 16) * Kpad;
  int k8 = g * 8;

  int s = s_lo;
  // unrolled-by-4 main body: 8 G-loads + 8 Yt-loads issued before any use
  for (; s + 4 <= s_hi && (s + 4) * 32 <= K; s += 4) {
    f32x4 ga[8]; s16x8 yb[8];
    #pragma unroll
    for (int u = 0; u < 4; ++u) {
      int k = (s + u) * 32 + k8;
      ga[2*u]   = __builtin_nontemporal_load((const f32x4*)(gp + k));
      ga[2*u+1] = __builtin_nontemporal_load((const f32x4*)(gp + k + 4));
      yb[2*u]   = *(const s16x8*)(b0 + k);
      yb[2*u+1] = *(const s16x8*)(b1 + k);
    }
    #pragma unroll
    for (int u = 0; u < 4; ++u) {
      s16x8 a;
      a[0]=f2bf(ga[2*u].x); a[1]=f2bf(ga[2*u].y);
      a[2]=f2bf(ga[2*u].z); a[3]=f2bf(ga[2*u].w);
      a[4]=f2bf(ga[2*u+1].x); a[5]=f2bf(ga[2*u+1].y);
      a[6]=f2bf(ga[2*u+1].z); a[7]=f2bf(ga[2*u+1].w);
      acc0 = __builtin_amdgcn_mfma_f32_16x16x32_bf16(a, yb[2*u],   acc0, 0, 0, 0);
      acc1 = __builtin_amdgcn_mfma_f32_16x16x32_bf16(a, yb[2*u+1], acc1, 0, 0, 0);
    }
  }
  // remainder with tail masking
  for (; s < s_hi; ++s) {
    int k = s * 32 + k8;
    s16x8 a = {0,0,0,0,0,0,0,0};
    if (k < K) {
      f32x4 a0 = *(const f32x4*)(gp + k);
      f32x4 a1 = *(const f32x4*)(gp + k + 4);
      a[0]=f2bf(a0.x); a[1]=f2bf(a0.y); a[2]=f2bf(a0.z); a[3]=f2bf(a0.w);
      a[4]=f2bf(a1.x); a[5]=f2bf(a1.y); a[6]=f2bf(a1.z); a[7]=f2bf(a1.w);
    }
    s16x8 vb0 = *(const s16x8*)(b0 + k);
    s16x8 vb1 = *(const s16x8*)(b1 + k);
    acc0 = __builtin_amdgcn_mfma_f32_16x16x32_bf16(a, vb0, acc0, 0, 0, 0);
    acc1 = __builtin_amdgcn_mfma_f32_16x16x32_bf16(a, vb1, acc1, 0, 0, 0);
  }
}

__global__ __launch_bounds__(256) void gemm_skinny(
    const float* __restrict__ Gv2v, const float* __restrict__ Gv2e,
    const float* __restrict__ Ge2e, const float* __restrict__ Ge2f,
    const float* __restrict__ Gf2f, const short* __restrict__ Yt,
    float* __restrict__ out)
{
  int bid  = blockIdx.x;
  int lane = threadIdx.x & 63, w = threadIdx.x >> 6;

  const float *G0, *G1; const short *Y0, *Y1;
  int K0, Kp0, K1, Kp1, st0, st1, tile; size_t ob;
  if (bid < 500) {           // zf = Ge2f@Ye2f + Gf2f@Yf2f   (625 steps, heaviest first)
    tile = bid;
    G0 = Ge2f; Y0 = Yt + 769024;  K0 = 12000; Kp0 = 12000; st0 = 375;
    G1 = Gf2f; Y1 = Yt + 1153024; K1 = 8000;  Kp1 = 8000;  st1 = 250;
    ob = (size_t)18000 * 32;
  } else if (bid < 1250) {   // ze = Gv2e@Yv2e + Ge2e@Ye2e   (563 steps)
    tile = bid - 500;
    G0 = Gv2e; Y0 = Yt + 192512;  K0 = 6000;  Kp0 = 6016;  st0 = 188;
    G1 = Ge2e; Y1 = Yt + 385024;  K1 = 12000; Kp1 = 12000; st1 = 375;
    ob = (size_t)6000 * 32;
  } else {                   // zv = Gv2v@Yv2v               (188 steps)
    tile = bid - 1250;
    G0 = Gv2v; Y0 = Yt;           K0 = 6000;  Kp0 = 6016;  st0 = 188;
    G1 = nullptr; Y1 = nullptr;   K1 = 0; Kp1 = 0; st1 = 0;
    ob = 0;
  }
  int total = st0 + st1;
  int row0  = tile * 16;
  int s_lo  = (total * w) >> 2;
  int s_hi  = (total * (w + 1)) >> 2;

  f32x4 acc0 = {0.f,0.f,0.f,0.f}, acc1 = {0.f,0.f,0.f,0.f};
  int e0 = s_hi < st0 ? s_hi : st0;
  run_seg(G0, Y0, K0, Kp0, row0, s_lo, e0, lane, acc0, acc1);
  if (st1 > 0 && s_hi > st0) {
    int l1 = s_lo > st0 ? s_lo - st0 : 0;
    run_seg(G1, Y1, K1, Kp1, row0, l1, s_hi - st0, lane, acc0, acc1);
  }

  // cross-wave reduce: C/D layout: col = lane&15, row = (lane>>4)*4+reg
  __shared__ float red[4][512];
  int r = lane & 15, g = lane >> 4;
  #pragma unroll
  for (int q = 0; q < 4; ++q) {
    int rw = g * 4 + q;
    red[w][rw * 32 + r]      = acc0[q];
    red[w][rw * 32 + 16 + r] = acc1[q];
  }
  __syncthreads();
  #pragma unroll
  for (int i = 0; i < 2; ++i) {
    int e = (int)threadIdx.x + i * 256;
    float s = red[0][e] + red[1][e] + red[2][e] + red[3][e];
    out[ob + (size_t)row0 * 32 + e] = s;
  }
}

extern "C" void kernel_launch(void* const* d_in, const int* in_sizes, int n_in,
                              void* d_out, int out_size, void* d_ws, size_t ws_size,
                              hipStream_t stream) {
  const float* xv   = (const float*)d_in[0];
  const float* xe   = (const float*)d_in[1];
  const float* xf   = (const float*)d_in[2];
  const float* Gv2v = (const float*)d_in[3];
  const float* Gv2e = (const float*)d_in[4];
  const float* Ge2e = (const float*)d_in[5];
  const float* Ge2f = (const float*)d_in[6];
  const float* Gf2f = (const float*)d_in[7];
  const float* Wv2v = (const float*)d_in[8];
  const float* Wv2e = (const float*)d_in[9];
  const float* We2e = (const float*)d_in[10];
  const float* We2f = (const float*)d_in[11];
  const float* Wf2f = (const float*)d_in[12];
  short* Yt  = (short*)d_ws;
  float* out = (float*)d_out;

  hipLaunchKernelGGL(build_yt, dim3(174), dim3(256), 0, stream,
                     xv, xe, xf, Wv2v, Wv2e, We2e, We2f, Wf2f, Yt);
  hipLaunchKernelGGL(gemm_skinny, dim3(1625), dim3(256), 0, stream,
                     Gv2v, Gv2e, Ge2e, Ge2f, Gf2f, Yt, out);
}

// Round 3
// 385.755 us; speedup vs baseline: 1.3284x; 1.3284x over previous
//
#include <hip/hip_runtime.h>

typedef float  f32x4 __attribute__((ext_vector_type(4)));
typedef short  s16x8 __attribute__((ext_vector_type(8)));

#define PK   256   // panel K-span (floats)
#define PSTR 260   // padded LDS row stride (floats); 1040B = 16B-aligned, spreads banks

typedef const __attribute__((address_space(1))) float* gas1f;
typedef __attribute__((address_space(3))) float*       las3f;

__device__ __forceinline__ short f2bf(float f) {
  unsigned u = __builtin_bit_cast(unsigned, f);
  u += 0x7FFFu + ((u >> 16) & 1u);   // round-to-nearest-even
  return (short)(u >> 16);
}

// ---------------------------------------------------------------------------
// Kernel 1: Y^T build.  Yt[c][k] = bf16( sum_d x[k][d] * W[d][c] )
// Kpad is a multiple of 256 (panel size) and zero-filled, so the GEMM kernel
// needs no B-side tail masking.  Offsets (elements):
//  v2v: 0      Kpad 6144   (32*6144 = 196608)
//  v2e: 196608 Kpad 6144
//  e2e: 393216 Kpad 12032  (32*12032 = 385024)
//  e2f: 778240 Kpad 12032
//  f2f: 1163264 Kpad 8192  (end 1425408 elems = 2.85 MB)
// ---------------------------------------------------------------------------
__global__ __launch_bounds__(256) void build_yt(
    const float* __restrict__ xv, const float* __restrict__ xe,
    const float* __restrict__ xf,
    const float* __restrict__ Wv2v, const float* __restrict__ Wv2e,
    const float* __restrict__ We2e, const float* __restrict__ We2f,
    const float* __restrict__ Wf2f, short* __restrict__ Yt)
{
  int bid = blockIdx.x;
  const float* x; const float* W; int K, Kpad; size_t yoff;
  if (bid < 24)       { x=xv; W=Wv2v; K=6000;  Kpad=6144;  yoff=0;       }
  else if (bid < 48)  { x=xv; W=Wv2e; K=6000;  Kpad=6144;  yoff=196608;  bid-=24; }
  else if (bid < 95)  { x=xe; W=We2e; K=12000; Kpad=12032; yoff=393216;  bid-=48; }
  else if (bid < 142) { x=xe; W=We2f; K=12000; Kpad=12032; yoff=778240;  bid-=95; }
  else                { x=xf; W=Wf2f; K=8000;  Kpad=8192;  yoff=1163264; bid-=142; }

  __shared__ float Wl[32][32];
  int tid = threadIdx.x;
  #pragma unroll
  for (int i = 0; i < 4; ++i) {
    int e = tid + i * 256;
    Wl[e >> 5][e & 31] = W[e];
  }
  __syncthreads();

  int row = bid * 256 + tid;
  if (row >= Kpad) return;

  float acc[32];
  #pragma unroll
  for (int c = 0; c < 32; ++c) acc[c] = 0.f;

  if (row < K) {
    const float* xp = x + (size_t)row * 32;
    float xr[32];
    #pragma unroll
    for (int i = 0; i < 8; ++i) {
      f32x4 v = *(const f32x4*)(xp + i * 4);
      xr[i*4+0] = v.x; xr[i*4+1] = v.y; xr[i*4+2] = v.z; xr[i*4+3] = v.w;
    }
    #pragma unroll
    for (int d = 0; d < 32; ++d) {
      float xd = xr[d];
      #pragma unroll
      for (int c = 0; c < 32; ++c) acc[c] += xd * Wl[d][c];
    }
  }
  #pragma unroll
  for (int c = 0; c < 32; ++c)
    Yt[yoff + (size_t)c * Kpad + row] = f2bf(acc[c]);
}

// ---------------------------------------------------------------------------
// Kernel 2: skinny GEMM, LDS-panel staged A for DRAM page locality.
// Per panel: 16 rows x 256 floats (16 KB), staged via 16x global_load_lds
// (each = 1 KB CONTIGUOUS from one G row), double-buffered, 1 barrier/panel.
// Waves split the 8 k-steps of a panel (2 each); cross-wave LDS reduce at end.
// ---------------------------------------------------------------------------
__device__ __forceinline__ void seg_run(
    const float* __restrict__ G, const short* __restrict__ Yt,
    int K, int Kpad, int row0, int lane, int w,
    float (*panel)[16][PSTR], f32x4& acc0, f32x4& acc1)
{
  int np = (K + PK - 1) / PK;
  int r = lane & 15, g = lane >> 4;

  // prologue: stage panel 0 (K >= 6000, always a full panel)
  {
    const float* base = G + (size_t)row0 * K;
    #pragma unroll
    for (int j = 0; j < 4; ++j) {
      int rr = 4 * w + j;
      __builtin_amdgcn_global_load_lds((gas1f)(base + (size_t)rr * K + lane * 4),
                                       (las3f)&panel[0][rr][0], 16, 0, 2 /*nt*/);
    }
  }
  __syncthreads();

  for (int p = 0; p < np; ++p) {
    int b = p & 1;
    int pn = p + 1;
    if (pn < np) {
      if (pn * PK + PK <= K) {        // full panel: 1KB-per-row bursts
        const float* base = G + (size_t)row0 * K + (size_t)pn * PK;
        #pragma unroll
        for (int j = 0; j < 4; ++j) {
          int rr = 4 * w + j;
          __builtin_amdgcn_global_load_lds((gas1f)(base + (size_t)rr * K + lane * 4),
                                           (las3f)&panel[b ^ 1][rr][0], 16, 0, 2);
        }
      } else {                         // tail panel: reg-staged, masked, zero-padded
        #pragma unroll
        for (int j = 0; j < 4; ++j) {
          int rr = 4 * w + j;
          int k = pn * PK + lane * 4;
          f32x4 v = {0.f, 0.f, 0.f, 0.f};
          if (k < K) v = *(const f32x4*)(G + (size_t)(row0 + rr) * K + k);
          *(f32x4*)&panel[b ^ 1][rr][lane * 4] = v;
        }
      }
    }
    // compute panel p: wave w owns k-steps {2w, 2w+1}
    #pragma unroll
    for (int si = 0; si < 2; ++si) {
      int s  = 2 * w + si;
      int kk = s * 32 + g * 8;
      f32x4 a0 = *(const f32x4*)&panel[b][r][kk];
      f32x4 a1 = *(const f32x4*)&panel[b][r][kk + 4];
      s16x8 a;
      a[0] = f2bf(a0.x); a[1] = f2bf(a0.y); a[2] = f2bf(a0.z); a[3] = f2bf(a0.w);
      a[4] = f2bf(a1.x); a[5] = f2bf(a1.y); a[6] = f2bf(a1.z); a[7] = f2bf(a1.w);
      int kg = p * PK + kk;
      s16x8 vb0 = *(const s16x8*)(Yt + (size_t)r * Kpad + kg);
      s16x8 vb1 = *(const s16x8*)(Yt + (size_t)(r + 16) * Kpad + kg);
      acc0 = __builtin_amdgcn_mfma_f32_16x16x32_bf16(a, vb0, acc0, 0, 0, 0);
      acc1 = __builtin_amdgcn_mfma_f32_16x16x32_bf16(a, vb1, acc1, 0, 0, 0);
    }
    __syncthreads();   // drains stage(p+1) loads + guards dbuf swap
  }
}

__global__ __launch_bounds__(256) void gemm_skinny(
    const float* __restrict__ Gv2v, const float* __restrict__ Gv2e,
    const float* __restrict__ Ge2e, const float* __restrict__ Ge2f,
    const float* __restrict__ Gf2f, const short* __restrict__ Yt,
    float* __restrict__ out)
{
  __shared__ float panel[2][16][PSTR];   // 33,280 B; reused as reduce buffer

  int bid  = blockIdx.x;
  int lane = threadIdx.x & 63, w = threadIdx.x >> 6;

  const float *G0, *G1; const short *Y0, *Y1;
  int K0, Kp0, K1, Kp1, tile; size_t ob;
  if (bid < 500) {           // zf = Ge2f@Ye2f + Gf2f@Yf2f  (K total 20000, heaviest)
    tile = bid;
    G0 = Ge2f; Y0 = Yt + 778240;  K0 = 12000; Kp0 = 12032;
    G1 = Gf2f; Y1 = Yt + 1163264; K1 = 8000;  Kp1 = 8192;
    ob = (size_t)18000 * 32;
  } else if (bid < 1250) {   // ze = Gv2e@Yv2e + Ge2e@Ye2e  (K total 18000)
    tile = bid - 500;
    G0 = Gv2e; Y0 = Yt + 196608;  K0 = 6000;  Kp0 = 6144;
    G1 = Ge2e; Y1 = Yt + 393216;  K1 = 12000; Kp1 = 12032;
    ob = (size_t)6000 * 32;
  } else {                   // zv = Gv2v@Yv2v              (K 6000)
    tile = bid - 1250;
    G0 = Gv2v; Y0 = Yt;           K0 = 6000;  Kp0 = 6144;
    G1 = nullptr; Y1 = nullptr;   K1 = 0; Kp1 = 0;
    ob = 0;
  }
  int row0 = tile * 16;

  f32x4 acc0 = {0.f,0.f,0.f,0.f}, acc1 = {0.f,0.f,0.f,0.f};
  seg_run(G0, Y0, K0, Kp0, row0, lane, w, panel, acc0, acc1);
  if (G1) seg_run(G1, Y1, K1, Kp1, row0, lane, w, panel, acc0, acc1);

  // cross-wave reduce (C/D layout: col = lane&15, row = (lane>>4)*4+reg)
  float (*red)[512] = (float (*)[512])panel;   // safe: last panel loop ended with sync
  int r = lane & 15, g = lane >> 4;
  #pragma unroll
  for (int q = 0; q < 4; ++q) {
    int rw = g * 4 + q;
    red[w][rw * 32 + r]      = acc0[q];
    red[w][rw * 32 + 16 + r] = acc1[q];
  }
  __syncthreads();
  #pragma unroll
  for (int i = 0; i < 2; ++i) {
    int e = (int)threadIdx.x + i * 256;
    float s = red[0][e] + red[1][e] + red[2][e] + red[3][e];
    out[ob + (size_t)row0 * 32 + e] = s;
  }
}

extern "C" void kernel_launch(void* const* d_in, const int* in_sizes, int n_in,
                              void* d_out, int out_size, void* d_ws, size_t ws_size,
                              hipStream_t stream) {
  const float* xv   = (const float*)d_in[0];
  const float* xe   = (const float*)d_in[1];
  const float* xf   = (const float*)d_in[2];
  const float* Gv2v = (const float*)d_in[3];
  const float* Gv2e = (const float*)d_in[4];
  const float* Ge2e = (const float*)d_in[5];
  const float* Ge2f = (const float*)d_in[6];
  const float* Gf2f = (const float*)d_in[7];
  const float* Wv2v = (const float*)d_in[8];
  const float* Wv2e = (const float*)d_in[9];
  const float* We2e = (const float*)d_in[10];
  const float* We2f = (const float*)d_in[11];
  const float* Wf2f = (const float*)d_in[12];
  short* Yt  = (short*)d_ws;
  float* out = (float*)d_out;

  hipLaunchKernelGGL(build_yt, dim3(174), dim3(256), 0, stream,
                     xv, xe, xf, Wv2v, Wv2e, We2e, We2f, Wf2f, Yt);
  hipLaunchKernelGGL(gemm_skinny, dim3(1625), dim3(256), 0, stream,
                     Gv2v, Gv2e, Ge2e, Ge2f, Gf2f, Yt, out);
}

// Round 4
// 356.278 us; speedup vs baseline: 1.4383x; 1.0827x over previous
//
#include <hip/hip_runtime.h>

typedef float  f32x4 __attribute__((ext_vector_type(4)));
typedef short  s16x8 __attribute__((ext_vector_type(8)));

#define PK   256   // panel K-span (floats)
#define PSTR 260   // padded LDS row stride (floats)

typedef const __attribute__((address_space(1))) float* gas1f;
typedef __attribute__((address_space(3))) float*       las3f;

__device__ __forceinline__ short f2bf(float f) {
  unsigned u = __builtin_bit_cast(unsigned, f);
  u += 0x7FFFu + ((u >> 16) & 1u);   // round-to-nearest-even
  return (short)(u >> 16);
}

// ---------------------------------------------------------------------------
// Kernel 1: Y^T build.  Yt[c][k] = bf16( sum_d x[k][d] * W[d][c] )
// Kpad multiple of 256, zero-filled.  Offsets (elements):
//  v2v 0 (Kpad 6144) | v2e 196608 | e2e 393216 (Kpad 12032) | e2f 778240
//  f2f 1163264 (Kpad 8192); total 1425408 elems = 2.85 MB.
// ---------------------------------------------------------------------------
__global__ __launch_bounds__(256) void build_yt(
    const float* __restrict__ xv, const float* __restrict__ xe,
    const float* __restrict__ xf,
    const float* __restrict__ Wv2v, const float* __restrict__ Wv2e,
    const float* __restrict__ We2e, const float* __restrict__ We2f,
    const float* __restrict__ Wf2f, short* __restrict__ Yt)
{
  int bid = blockIdx.x;
  const float* x; const float* W; int K, Kpad; size_t yoff;
  if (bid < 24)       { x=xv; W=Wv2v; K=6000;  Kpad=6144;  yoff=0;       }
  else if (bid < 48)  { x=xv; W=Wv2e; K=6000;  Kpad=6144;  yoff=196608;  bid-=24; }
  else if (bid < 95)  { x=xe; W=We2e; K=12000; Kpad=12032; yoff=393216;  bid-=48; }
  else if (bid < 142) { x=xe; W=We2f; K=12000; Kpad=12032; yoff=778240;  bid-=95; }
  else                { x=xf; W=Wf2f; K=8000;  Kpad=8192;  yoff=1163264; bid-=142; }

  __shared__ float Wl[32][32];
  int tid = threadIdx.x;
  #pragma unroll
  for (int i = 0; i < 4; ++i) {
    int e = tid + i * 256;
    Wl[e >> 5][e & 31] = W[e];
  }
  __syncthreads();

  int row = bid * 256 + tid;
  if (row >= Kpad) return;

  float acc[32];
  #pragma unroll
  for (int c = 0; c < 32; ++c) acc[c] = 0.f;

  if (row < K) {
    const float* xp = x + (size_t)row * 32;
    float xr[32];
    #pragma unroll
    for (int i = 0; i < 8; ++i) {
      f32x4 v = *(const f32x4*)(xp + i * 4);
      xr[i*4+0] = v.x; xr[i*4+1] = v.y; xr[i*4+2] = v.z; xr[i*4+3] = v.w;
    }
    #pragma unroll
    for (int d = 0; d < 32; ++d) {
      float xd = xr[d];
      #pragma unroll
      for (int c = 0; c < 32; ++c) acc[c] += xd * Wl[d][c];
    }
  }
  #pragma unroll
  for (int c = 0; c < 32; ++c)
    Yt[yoff + (size_t)c * Kpad + row] = f2bf(acc[c]);
}

// ---------------------------------------------------------------------------
// Kernel 2: skinny GEMM, LDS-panel staged A, COUNTED-vmcnt double-buffer
// pipeline (T3/T4): never drain the DMA queue to 0 inside the loop.
//   iter p: vmcnt(4 or 0) -> s_barrier -> compute(p) -> lgkmcnt(0)
//           -> sched_barrier -> s_barrier -> stage(p+2) into buf p&1
// ---------------------------------------------------------------------------
__device__ __forceinline__ void stage_panel(
    const float* __restrict__ G, int K, int row0, int pn, int lane, int w,
    float (*panel)[16][PSTR], int bb)
{
  if ((pn + 1) * PK <= K) {            // full panel: 1KB-per-row DMA bursts
    const float* base = G + (size_t)row0 * K + (size_t)pn * PK;
    #pragma unroll
    for (int j = 0; j < 4; ++j) {
      int rr = 4 * w + j;
      __builtin_amdgcn_global_load_lds((gas1f)(base + (size_t)rr * K + lane * 4),
                                       (las3f)&panel[bb][rr][0], 16, 0, 2 /*nt*/);
    }
  } else {                             // tail panel: reg-staged, masked, zeroed
    #pragma unroll
    for (int j = 0; j < 4; ++j) {
      int rr = 4 * w + j;
      int k = pn * PK + lane * 4;
      f32x4 v = {0.f, 0.f, 0.f, 0.f};
      if (k < K) v = *(const f32x4*)(G + (size_t)(row0 + rr) * K + k);
      *(f32x4*)&panel[bb][rr][lane * 4] = v;
    }
  }
}

__device__ __forceinline__ void seg_run(
    const float* __restrict__ G, const short* __restrict__ Yt,
    int K, int Kpad, int row0, int lane, int w,
    float (*panel)[16][PSTR], f32x4& acc0, f32x4& acc1)
{
  int np = (K + PK - 1) / PK;          // >= 24 for all segments
  int r = lane & 15, g = lane >> 4;

  stage_panel(G, K, row0, 0, lane, w, panel, 0);
  stage_panel(G, K, row0, 1, lane, w, panel, 1);

  for (int p = 0; p < np; ++p) {
    // wait for panel p's loads; leave panel p+1's DMAs (if any) in flight
    if (p + 1 < np && (p + 2) * PK <= K)
      asm volatile("s_waitcnt vmcnt(4)" ::: "memory");
    else
      asm volatile("s_waitcnt vmcnt(0)" ::: "memory");
    __builtin_amdgcn_s_barrier();

    int b = p & 1;
    #pragma unroll
    for (int si = 0; si < 2; ++si) {
      int s  = 2 * w + si;
      int kk = s * 32 + g * 8;
      f32x4 a0 = *(const f32x4*)&panel[b][r][kk];
      f32x4 a1 = *(const f32x4*)&panel[b][r][kk + 4];
      s16x8 a;
      a[0] = f2bf(a0.x); a[1] = f2bf(a0.y); a[2] = f2bf(a0.z); a[3] = f2bf(a0.w);
      a[4] = f2bf(a1.x); a[5] = f2bf(a1.y); a[6] = f2bf(a1.z); a[7] = f2bf(a1.w);
      int kg = p * PK + kk;
      s16x8 vb0 = *(const s16x8*)(Yt + (size_t)r * Kpad + kg);
      s16x8 vb1 = *(const s16x8*)(Yt + (size_t)(r + 16) * Kpad + kg);
      acc0 = __builtin_amdgcn_mfma_f32_16x16x32_bf16(a, vb0, acc0, 0, 0, 0);
      acc1 = __builtin_amdgcn_mfma_f32_16x16x32_bf16(a, vb1, acc1, 0, 0, 0);
    }

    asm volatile("s_waitcnt lgkmcnt(0)" ::: "memory");
    __builtin_amdgcn_sched_barrier(0);
    __builtin_amdgcn_s_barrier();      // all waves done reading buf b
    if (p + 2 < np) stage_panel(G, K, row0, p + 2, lane, w, panel, b);
  }
  __syncthreads();                     // segment epilogue: full drain
}

__global__ __launch_bounds__(256) void gemm_skinny(
    const float* __restrict__ Gv2v, const float* __restrict__ Gv2e,
    const float* __restrict__ Ge2e, const float* __restrict__ Ge2f,
    const float* __restrict__ Gf2f, const short* __restrict__ Yt,
    float* __restrict__ out)
{
  __shared__ float panel[2][16][PSTR];   // 33,280 B; reused as reduce buffer

  int bid  = blockIdx.x;
  int lane = threadIdx.x & 63, w = threadIdx.x >> 6;

  const float *G0, *G1; const short *Y0, *Y1;
  int K0, Kp0, K1, Kp1, tile; size_t ob;
  if (bid < 500) {           // zf = Ge2f@Ye2f + Gf2f@Yf2f  (K total 20000)
    tile = bid;
    G0 = Ge2f; Y0 = Yt + 778240;  K0 = 12000; Kp0 = 12032;
    G1 = Gf2f; Y1 = Yt + 1163264; K1 = 8000;  Kp1 = 8192;
    ob = (size_t)18000 * 32;
  } else if (bid < 1250) {   // ze = Gv2e@Yv2e + Ge2e@Ye2e  (K total 18000)
    tile = bid - 500;
    G0 = Gv2e; Y0 = Yt + 196608;  K0 = 6000;  Kp0 = 6144;
    G1 = Ge2e; Y1 = Yt + 393216;  K1 = 12000; Kp1 = 12032;
    ob = (size_t)6000 * 32;
  } else {                   // zv = Gv2v@Yv2v              (K 6000)
    tile = bid - 1250;
    G0 = Gv2v; Y0 = Yt;           K0 = 6000;  Kp0 = 6144;
    G1 = nullptr; Y1 = nullptr;   K1 = 0; Kp1 = 0;
    ob = 0;
  }
  int row0 = tile * 16;

  f32x4 acc0 = {0.f,0.f,0.f,0.f}, acc1 = {0.f,0.f,0.f,0.f};
  seg_run(G0, Y0, K0, Kp0, row0, lane, w, panel, acc0, acc1);
  if (G1) seg_run(G1, Y1, K1, Kp1, row0, lane, w, panel, acc0, acc1);

  // cross-wave reduce (C/D layout: col = lane&15, row = (lane>>4)*4+reg)
  float (*red)[512] = (float (*)[512])panel;   // safe: seg_run ends synced
  int r = lane & 15, g = lane >> 4;
  #pragma unroll
  for (int q = 0; q < 4; ++q) {
    int rw = g * 4 + q;
    red[w][rw * 32 + r]      = acc0[q];
    red[w][rw * 32 + 16 + r] = acc1[q];
  }
  __syncthreads();
  #pragma unroll
  for (int i = 0; i < 2; ++i) {
    int e = (int)threadIdx.x + i * 256;
    float s = red[0][e] + red[1][e] + red[2][e] + red[3][e];
    out[ob + (size_t)row0 * 32 + e] = s;
  }
}

extern "C" void kernel_launch(void* const* d_in, const int* in_sizes, int n_in,
                              void* d_out, int out_size, void* d_ws, size_t ws_size,
                              hipStream_t stream) {
  const float* xv   = (const float*)d_in[0];
  const float* xe   = (const float*)d_in[1];
  const float* xf   = (const float*)d_in[2];
  const float* Gv2v = (const float*)d_in[3];
  const float* Gv2e = (const float*)d_in[4];
  const float* Ge2e = (const float*)d_in[5];
  const float* Ge2f = (const float*)d_in[6];
  const float* Gf2f = (const float*)d_in[7];
  const float* Wv2v = (const float*)d_in[8];
  const float* Wv2e = (const float*)d_in[9];
  const float* We2e = (const float*)d_in[10];
  const float* We2f = (const float*)d_in[11];
  const float* Wf2f = (const float*)d_in[12];
  short* Yt  = (short*)d_ws;
  float* out = (float*)d_out;

  hipLaunchKernelGGL(build_yt, dim3(174), dim3(256), 0, stream,
                     xv, xe, xf, Wv2v, Wv2e, We2e, We2f, Wf2f, Yt);
  hipLaunchKernelGGL(gemm_skinny, dim3(1625), dim3(256), 0, stream,
                     Gv2v, Gv2e, Ge2e, Ge2f, Gf2f, Yt, out);
}